// Round 17
// baseline (2149.188 us; speedup 1.0000x reference)
//
#include <hip/hip_runtime.h>
#include <hip/hip_bf16.h>
#include <stdint.h>

#define T_STEPS 512
#define BATCH   64
#define IN_DIM  512
#define H_DIM   1024
#define KDIM    1536
#define NWG     256
#define NTHREADS 256

// LDS layout (bytes)
#define WLDS_OFF 0
#define WLDS_BYTES (24*4*64*16)       // 98304: B-frags ksteps 0..23, 4 gates
#define HA_OFF   98304                // 32768: h tile, frag order: slot = ks*64+lane
#define XA_OFF   131072               // 16384: x tile, frag order
#define SMZ_OFF  147456               // 16*65*4 = 4160
#define LDS_TOTAL 151616

// ws layout (bytes). sync ints: barr[bt]@bt*64 (4 flat per-bt counters, 256B apart)
#define WS_SYNC 0
#define WS_HB   32768           // ping-pong h, 2*64*1024 bf16 = 262144 B
#define WS_XB   294912          // x as bf16 = 33554432 B
#define WS_WPK  33849344        // packed weights 12582912 B

typedef float  f32x4  __attribute__((ext_vector_type(4)));
typedef short  short8 __attribute__((ext_vector_type(8)));
typedef int    int4v  __attribute__((ext_vector_type(4)));
typedef __bf16 bf16x8 __attribute__((ext_vector_type(8)));

__device__ __forceinline__ short f2bf(float f) {
    union { float f; unsigned u; } x; x.f = f;
    unsigned r = (x.u + 0x7fffu + ((x.u >> 16) & 1u)) >> 16;
    return (short)r;
}
__device__ __forceinline__ f32x4 bmfma(short8 a, short8 b, f32x4 c) {
    return __builtin_amdgcn_mfma_f32_16x16x32_bf16(
        __builtin_bit_cast(bf16x8, a), __builtin_bit_cast(bf16x8, b), c, 0, 0, 0);
}

// W[g] fp32 [1024][1536] -> B-frag order per 16-col group (proven R9-R16):
// Wpk[(((cb*48+ks)*4+g)*64 + grp*16+n)*8 + u] = bf16(W[g][cb*16+n][ks*32+grp*8+u])
__global__ __launch_bounds__(256) void pack_w_kernel(const float* __restrict__ W,
                                                     short* __restrict__ Wpk, int g) {
    int e = blockIdx.x * 256 + threadIdx.x;       // < 1024*1536
    int j = e / KDIM, k = e - j * KDIM;
    int cb = j >> 4, n = j & 15;
    int ks = k >> 5, grp = (k & 31) >> 3, u = k & 7;
    size_t dst = (((size_t)(cb * 48 + ks) * 4 + g) * 64 + grp * 16 + n) * 8 + u;
    Wpk[dst] = f2bf(W[e]);
}

__global__ __launch_bounds__(256) void xconv_kernel(const float* __restrict__ x,
                                                    short* __restrict__ xb) {
    size_t e = ((size_t)blockIdx.x * 256 + threadIdx.x) * 8;
    f32x4 v0 = *reinterpret_cast<const f32x4*>(x + e);
    f32x4 v1 = *reinterpret_cast<const f32x4*>(x + e + 4);
    short8 o;
    #pragma unroll
    for (int u = 0; u < 4; ++u) { o[u] = f2bf(v0[u]); o[4 + u] = f2bf(v1[u]); }
    *reinterpret_cast<short8*>(xb + e) = o;
}

__global__ __launch_bounds__(256) void init_state_kernel(int* sync, int* hb_i) {
    int e = blockIdx.x * 256 + threadIdx.x;
    if (e < 8192) sync[e] = 0;
    if (e < 65536) hb_i[e] = 0;                   // both h ping-pong buffers
}

extern "C" __global__ void __launch_bounds__(NTHREADS, 1)
lstm_persistent(const short* __restrict__ Wpk, const short* __restrict__ xb,
                short* __restrict__ hb, float* __restrict__ out,
                const float* __restrict__ bf_, const float* __restrict__ bi_,
                const float* __restrict__ bc_, const float* __restrict__ bo_,
                int* __restrict__ sync)
{
    extern __shared__ char lds[];
    short* Wlds = (short*)(lds + WLDS_OFF);       // [24][4][64][8]
    short* hA   = (short*)(lds + HA_OFF);         // frag order: slot = ks*64 + lane
    short* xA   = (short*)(lds + XA_OFF);         // frag order
    float* smZ  = (float*)(lds + SMZ_OFF);        // [16][65]

    const int tid = threadIdx.x, w = tid >> 6, lane = tid & 63;
    const int wg = blockIdx.x;
    const int bt = wg >> 6, cb = wg & 63;         // wg = cb + 64*bt
    const int r = lane & 15, hi = lane >> 4;

    const int erow = tid >> 4, ecol = tid & 15;
    const int row_g = bt * 16 + erow, col_g = cb * 16 + ecol;
    const float bfv = bf_[col_g], biv = bi_[col_g], bcv = bc_[col_g], bov = bo_[col_g];
    float creg = 0.f;

    // staging lane permutation: lane loads row (tid&15), 16B-chunk (tid>>4)&3 of block q4
    const int srow = tid & 15, schunk = (tid >> 4) & 3;

    // flat per-bt barrier (proven R16)
    int* mybarr = sync + bt * 64;

    // ---- stage weight ksteps 0..23 into LDS once (96 KB contiguous copy) ----
    const short* wgrp = Wpk + (size_t)cb * (48 * 4 * 64 * 8);
    #pragma unroll
    for (int q = 0; q < 24; ++q) {
        int sl = q * 256 + tid;
        *reinterpret_cast<short8*>(Wlds + sl * 8) =
            *reinterpret_cast<const short8*>(wgrp + (size_t)sl * 8);
    }
    const short* wstream = wgrp + (((size_t)24 * 4 + w) * 64 + lane) * 8;

    // ---- stage x(0): frag-order (write slot = q*256+tid, canonical-contiguous) ----
    {
        const short* xt = xb + ((size_t)0 * BATCH + bt * 16) * IN_DIM;
        #pragma unroll
        for (int q = 0; q < 4; ++q) {
            int q4 = q * 4 + w;                   // 0..15
            int idx = q4 * 4 + schunk;            // 0..63
            short8 v = *reinterpret_cast<const short8*>(xt + (size_t)srow * IN_DIM + idx * 8);
            *reinterpret_cast<short8*>(&xA[(q * 256 + tid) * 8]) = v;
        }
    }

    for (int t = 0; t < T_STEPS; ++t) {
        // ---- detect: all 64 same-bt WGs have published h(t) (t=0: zeros) ----
        if (t > 0) {
            if (tid == 0) {
                while (__hip_atomic_load(mybarr, __ATOMIC_RELAXED, __HIP_MEMORY_SCOPE_AGENT) < 64 * t)
                    __builtin_amdgcn_s_sleep(1);
            }
        }
        __syncthreads();                          // also orders Wlds/xA/hA stage writes

        // ---- issue ALL h coherent loads into regs, overlap RT with x-MFMAs ----
        const short* hcur = hb + (size_t)(t & 1) * (BATCH * H_DIM);
        unsigned long long hlo[8], hhi[8];
        #pragma unroll
        for (int q = 0; q < 8; ++q) {
            int q4 = q * 4 + w;                   // 0..31
            int idx = q4 * 4 + schunk;            // 0..127
            const unsigned long long* src = reinterpret_cast<const unsigned long long*>(
                hcur + ((size_t)(bt * 16 + srow) << 10) + idx * 8);
            hlo[q] = __hip_atomic_load(src,     __ATOMIC_RELAXED, __HIP_MEMORY_SCOPE_AGENT);
            hhi[q] = __hip_atomic_load(src + 1, __ATOMIC_RELAXED, __HIP_MEMORY_SCOPE_AGENT);
        }
        __builtin_amdgcn_sched_barrier(0);        // loads issued before x-block

        f32x4 acc[4];
        #pragma unroll
        for (int c = 0; c < 4; ++c) acc[c] = (f32x4){0.f, 0.f, 0.f, 0.f};
        #pragma unroll
        for (int ksx = 0; ksx < 16; ++ksx) {      // x-MFMAs under the h-load shadow
            short8 a = *reinterpret_cast<const short8*>(&xA[(ksx * 64 + lane) * 8]);
            short8 b = *reinterpret_cast<const short8*>(wstream + (size_t)(8 + ksx) * 2048);
            acc[ksx & 3] = bmfma(a, b, acc[ksx & 3]);
        }
        __builtin_amdgcn_sched_barrier(0);        // keep ds_writes (and their waitcnt) below

        #pragma unroll
        for (int q = 0; q < 8; ++q) {             // single b128 store, canonical-contiguous
            unsigned long long tmp[2] = {hlo[q], hhi[q]};
            *reinterpret_cast<int4v*>(&hA[(q * 256 + tid) * 8]) =
                *reinterpret_cast<const int4v*>(tmp);
        }
        __syncthreads();

        // ---- h MFMAs: A canonical-contiguous from hA; B: ks<24 LDS, ks>=24 L2 stream ----
        #pragma unroll
        for (int ks = 0; ks < 24; ++ks) {
            short8 a = *reinterpret_cast<const short8*>(&hA[(ks * 64 + lane) * 8]);
            short8 b = *reinterpret_cast<const short8*>(Wlds + ((size_t)(ks * 4 + w) * 64 + lane) * 8);
            acc[ks & 3] = bmfma(a, b, acc[ks & 3]);
        }
        #pragma unroll
        for (int ks = 24; ks < 32; ++ks) {
            short8 a = *reinterpret_cast<const short8*>(&hA[(ks * 64 + lane) * 8]);
            short8 b = *reinterpret_cast<const short8*>(wstream + (size_t)(ks - 24) * 2048);
            acc[ks & 3] = bmfma(a, b, acc[ks & 3]);
        }

        // ---- gather z across waves (wave w = gate w) ----
        f32x4 z4 = (acc[0] + acc[1]) + (acc[2] + acc[3]);
        #pragma unroll
        for (int i = 0; i < 4; ++i)               // C layout: col=lane&15, row=hi*4+i
            smZ[(hi * 4 + i) * 65 + w * 16 + r] = z4[i];
        __syncthreads();

        float zf = smZ[erow * 65 + ecol]      + bfv;
        float zi = smZ[erow * 65 + 16 + ecol] + biv;
        float zc = smZ[erow * 65 + 32 + ecol] + bcv;
        float zo = smZ[erow * 65 + 48 + ecol] + bov;
        float fg  = 1.f / (1.f + __expf(-zf));
        float ig  = 1.f / (1.f + __expf(-zi));
        float cg_ = 2.f / (1.f + __expf(-2.f * zc)) - 1.f;
        float og  = 1.f / (1.f + __expf(-zo));
        creg = fg * creg + ig * cg_;
        float nh = og * (2.f / (1.f + __expf(-2.f * creg)) - 1.f);

        // ---- publish h (write-through agent stores, proven) + out (NT) ----
        unsigned mybits = (unsigned)(unsigned short)f2bf(nh);
        unsigned pbits  = __shfl_xor(mybits, 1);  // partner col (ecol^1), same row
        short* hnext = hb + (size_t)((t + 1) & 1) * (BATCH * H_DIM);
        if ((tid & 1) == 0) {
            unsigned val = mybits | (pbits << 16);
            __hip_atomic_store(reinterpret_cast<unsigned*>(hnext + (size_t)row_g * H_DIM + col_g),
                               val, __ATOMIC_RELAXED, __HIP_MEMORY_SCOPE_AGENT);
        }
        __builtin_nontemporal_store(nh, out + (size_t)t * (BATCH * H_DIM) + (size_t)row_g * H_DIM + col_g);

        // ---- arrive: drain stores, ONE flat RMW on my bt-line ----
        __syncthreads();
        if (tid == 0)
            __hip_atomic_fetch_add(mybarr, 1, __ATOMIC_RELAXED, __HIP_MEMORY_SCOPE_AGENT);

        // ---- shadow: stage x(t+1) (frag order) while others arrive ----
        if (t + 1 < T_STEPS) {
            const short* xt = xb + ((size_t)(t + 1) * BATCH + bt * 16) * IN_DIM;
            #pragma unroll
            for (int q = 0; q < 4; ++q) {
                int q4 = q * 4 + w;
                int idx = q4 * 4 + schunk;
                short8 v = *reinterpret_cast<const short8*>(xt + (size_t)srow * IN_DIM + idx * 8);
                *reinterpret_cast<short8*>(&xA[(q * 256 + tid) * 8]) = v;
            }
        }
    }
}

extern "C" void kernel_launch(void* const* d_in, const int* in_sizes, int n_in,
                              void* d_out, int out_size, void* d_ws, size_t ws_size,
                              hipStream_t stream) {
    const float* x   = (const float*)d_in[0];
    const float* Wf  = (const float*)d_in[1];
    const float* Wi  = (const float*)d_in[2];
    const float* Wc  = (const float*)d_in[3];
    const float* Wo  = (const float*)d_in[4];
    const float* bf_ = (const float*)d_in[5];
    const float* bi_ = (const float*)d_in[6];
    const float* bc_ = (const float*)d_in[7];
    const float* bo_ = (const float*)d_in[8];
    float* out = (float*)d_out;

    char*  ws    = (char*)d_ws;
    int*   syncp = (int*)(ws + WS_SYNC);
    short* hbuf  = (short*)(ws + WS_HB);
    short* xb    = (short*)(ws + WS_XB);
    short* Wpk   = (short*)(ws + WS_WPK);

    hipFuncSetAttribute((const void*)lstm_persistent,
                        hipFuncAttributeMaxDynamicSharedMemorySize, LDS_TOTAL);

    const float* Ws[4] = {Wf, Wi, Wc, Wo};
    for (int g = 0; g < 4; ++g)
        pack_w_kernel<<<(H_DIM * KDIM) / 256, 256, 0, stream>>>(Ws[g], Wpk, g);
    xconv_kernel<<<(T_STEPS * BATCH * IN_DIM) / (256 * 8), 256, 0, stream>>>(x, xb);
    init_state_kernel<<<256, 256, 0, stream>>>(syncp, (int*)hbuf);

    const short* Wpk_c = Wpk; const short* xb_c = xb;
    void* args[] = {(void*)&Wpk_c, (void*)&xb_c, (void*)&hbuf, (void*)&out,
                    (void*)&bf_, (void*)&bi_, (void*)&bc_, (void*)&bo_, (void*)&syncp};
    hipLaunchCooperativeKernel((const void*)lstm_persistent, dim3(NWG), dim3(NTHREADS),
                               args, LDS_TOTAL, stream);
}

// Round 18
// 1556.285 us; speedup vs baseline: 1.3810x; 1.3810x over previous
//
#include <hip/hip_runtime.h>
#include <hip/hip_bf16.h>
#include <stdint.h>

#define T_STEPS 512
#define BATCH   64
#define IN_DIM  512
#define H_DIM   1024
#define KDIM    1536
#define NWG     256
#define NTHREADS 256

// LDS layout (bytes)
#define WLDS_OFF 0
#define WLDS_BYTES (24*4*64*16)       // 98304: B-frags ksteps 0..23, 4 gates
#define HA_OFF   98304                // 32768: h tile, canonical frag order
#define XA_OFF   131072               // 16384: x tile, canonical frag order
#define SMZ_OFF  147456               // 16*65*4 = 4160
#define LDS_TOTAL 151616

// ws layout (bytes). sync ints: barr[bt]@bt*64 (4 flat per-bt counters, 256B apart)
// hb/xb are stored in FRAG ORDER per bt-tile: (row,col) -> tile[ks*64+grp*16+row][8]
// with ks=col>>5, grp=(col>>3)&3, u=col&7. Tile = 16 rows x (H or IN) cols.
#define WS_SYNC 0
#define WS_HB   32768           // ping-pong h, 2*64*1024 bf16 = 262144 B
#define WS_XB   294912          // x as bf16 = 33554432 B
#define WS_WPK  33849344        // packed weights 12582912 B

typedef float  f32x4  __attribute__((ext_vector_type(4)));
typedef short  short8 __attribute__((ext_vector_type(8)));
typedef int    int4v  __attribute__((ext_vector_type(4)));
typedef __bf16 bf16x8 __attribute__((ext_vector_type(8)));

__device__ __forceinline__ short f2bf(float f) {
    union { float f; unsigned u; } x; x.f = f;
    unsigned r = (x.u + 0x7fffu + ((x.u >> 16) & 1u)) >> 16;
    return (short)r;
}
__device__ __forceinline__ f32x4 bmfma(short8 a, short8 b, f32x4 c) {
    return __builtin_amdgcn_mfma_f32_16x16x32_bf16(
        __builtin_bit_cast(bf16x8, a), __builtin_bit_cast(bf16x8, b), c, 0, 0, 0);
}

// W[g] fp32 [1024][1536] -> B-frag order per 16-col group (proven R9-R17):
// Wpk[(((cb*48+ks)*4+g)*64 + grp*16+n)*8 + u] = bf16(W[g][cb*16+n][ks*32+grp*8+u])
__global__ __launch_bounds__(256) void pack_w_kernel(const float* __restrict__ W,
                                                     short* __restrict__ Wpk, int g) {
    int e = blockIdx.x * 256 + threadIdx.x;       // < 1024*1536
    int j = e / KDIM, k = e - j * KDIM;
    int cb = j >> 4, n = j & 15;
    int ks = k >> 5, grp = (k & 31) >> 3, u = k & 7;
    size_t dst = (((size_t)(cb * 48 + ks) * 4 + g) * 64 + grp * 16 + n) * 8 + u;
    Wpk[dst] = f2bf(W[e]);
}

// x fp32 [T*64][512] -> xb frag-order tiles: xb[(t*4+bt)*1024 + ks*64+grp*16+row][8]
__global__ __launch_bounds__(256) void xconv_kernel(const float* __restrict__ x,
                                                    short* __restrict__ xb) {
    int e = blockIdx.x * 256 + threadIdx.x;       // chunk id < 512*64*64
    int t = e >> 12, rem = e & 4095;
    int brow = rem >> 6, chunk = rem & 63;
    const float* src = x + ((size_t)t * 64 + brow) * IN_DIM + chunk * 8;
    f32x4 v0 = *reinterpret_cast<const f32x4*>(src);
    f32x4 v1 = *reinterpret_cast<const f32x4*>(src + 4);
    short8 o;
    #pragma unroll
    for (int u = 0; u < 4; ++u) { o[u] = f2bf(v0[u]); o[4 + u] = f2bf(v1[u]); }
    int bt = brow >> 4, row = brow & 15, ks = chunk >> 2, grp = chunk & 3;
    size_t dst = (((size_t)t * 4 + bt) * 1024 + ks * 64 + grp * 16 + row) * 8;
    *reinterpret_cast<short8*>(xb + dst) = o;
}

__global__ __launch_bounds__(256) void init_state_kernel(int* sync, int* hb_i) {
    int e = blockIdx.x * 256 + threadIdx.x;
    if (e < 8192) sync[e] = 0;
    if (e < 65536) hb_i[e] = 0;                   // both h ping-pong buffers
}

extern "C" __global__ void __launch_bounds__(NTHREADS, 1)
lstm_persistent(const short* __restrict__ Wpk, const short* __restrict__ xb,
                short* __restrict__ hb, float* __restrict__ out,
                const float* __restrict__ bf_, const float* __restrict__ bi_,
                const float* __restrict__ bc_, const float* __restrict__ bo_,
                int* __restrict__ sync)
{
    extern __shared__ char lds[];
    short* Wlds = (short*)(lds + WLDS_OFF);       // [24][4][64][8]
    short* hA   = (short*)(lds + HA_OFF);         // canonical: slot = ks*64+lane
    short* xA   = (short*)(lds + XA_OFF);         // canonical
    float* smZ  = (float*)(lds + SMZ_OFF);        // [16][65]

    const int tid = threadIdx.x, w = tid >> 6, lane = tid & 63;
    const int wg = blockIdx.x;
    const int bt = wg >> 6, cb = wg & 63;         // wg = cb + 64*bt
    const int r = lane & 15, hi = lane >> 4;

    const int erow = tid >> 4, ecol = tid & 15;
    const int col_g = cb * 16 + ecol;
    const int row_g = bt * 16 + erow;
    const float bfv = bf_[col_g], biv = bi_[col_g], bcv = bc_[col_g], bov = bo_[col_g];
    float creg = 0.f;

    // h-publish target in frag order (col even for storing threads)
    const int chunkP = col_g >> 3, uP = col_g & 7;
    const int ksP = chunkP >> 2, grpP = chunkP & 3;
    const int pub_off = (ksP * 64 + grpP * 16 + erow) * 8 + uP;  // shorts within bt-tile

    // flat per-bt barrier (proven R16)
    int* mybarr = sync + bt * 64;

    // ---- stage weight ksteps 0..23 into LDS once (96 KB contiguous copy) ----
    const short* wgrp = Wpk + (size_t)cb * (48 * 4 * 64 * 8);
    #pragma unroll
    for (int q = 0; q < 24; ++q) {
        int sl = q * 256 + tid;
        *reinterpret_cast<short8*>(Wlds + sl * 8) =
            *reinterpret_cast<const short8*>(wgrp + (size_t)sl * 8);
    }
    const short* wstream = wgrp + (((size_t)24 * 4 + w) * 64 + lane) * 8;

    // ---- stage x(0): frag-order tile, contiguous read AND write ----
    {
        const short* xtile = xb + ((size_t)0 * 4 + bt) * (1024 * 8);
        #pragma unroll
        for (int q = 0; q < 4; ++q) {
            int sl = q * 256 + tid;
            *reinterpret_cast<short8*>(&xA[sl * 8]) =
                *reinterpret_cast<const short8*>(xtile + (size_t)sl * 8);
        }
    }

    for (int t = 0; t < T_STEPS; ++t) {
        // ---- detect: all 64 same-bt WGs have published h(t) (t=0: zeros) ----
        if (t > 0) {
            if (tid == 0) {
                while (__hip_atomic_load(mybarr, __ATOMIC_RELAXED, __HIP_MEMORY_SCOPE_AGENT) < 64 * t)
                    __builtin_amdgcn_s_sleep(1);
            }
        }
        __syncthreads();                          // also orders Wlds/xA/hA stage writes

        // ---- h coherent loads: frag-order tile -> 1KB contiguous per wave per q ----
        const short* htile = hb + (size_t)(t & 1) * (BATCH * H_DIM) + bt * 16384;
        unsigned long long hlo[8], hhi[8];
        #pragma unroll
        for (int q = 0; q < 8; ++q) {
            const unsigned long long* src = reinterpret_cast<const unsigned long long*>(
                htile + (size_t)(q * 256 + tid) * 8);
            hlo[q] = __hip_atomic_load(src,     __ATOMIC_RELAXED, __HIP_MEMORY_SCOPE_AGENT);
            hhi[q] = __hip_atomic_load(src + 1, __ATOMIC_RELAXED, __HIP_MEMORY_SCOPE_AGENT);
        }
        __builtin_amdgcn_sched_barrier(0);        // loads issued before x-block

        f32x4 acc[4];
        #pragma unroll
        for (int c = 0; c < 4; ++c) acc[c] = (f32x4){0.f, 0.f, 0.f, 0.f};
        #pragma unroll
        for (int ksx = 0; ksx < 16; ++ksx) {      // x-MFMAs under the h-load shadow
            short8 a = *reinterpret_cast<const short8*>(&xA[(ksx * 64 + lane) * 8]);
            short8 b = *reinterpret_cast<const short8*>(wstream + (size_t)(8 + ksx) * 2048);
            acc[ksx & 3] = bmfma(a, b, acc[ksx & 3]);
        }
        __builtin_amdgcn_sched_barrier(0);        // keep ds_writes (and their waitcnt) below

        #pragma unroll
        for (int q = 0; q < 8; ++q) {             // canonical-contiguous b128 stores
            unsigned long long tmp[2] = {hlo[q], hhi[q]};
            *reinterpret_cast<int4v*>(&hA[(q * 256 + tid) * 8]) =
                *reinterpret_cast<const int4v*>(tmp);
        }
        __syncthreads();

        // ---- h MFMAs: A canonical from hA; B: ks<24 LDS, ks>=24 warm-L2 stream ----
        #pragma unroll
        for (int ks = 0; ks < 24; ++ks) {
            short8 a = *reinterpret_cast<const short8*>(&hA[(ks * 64 + lane) * 8]);
            short8 b = *reinterpret_cast<const short8*>(Wlds + ((size_t)(ks * 4 + w) * 64 + lane) * 8);
            acc[ks & 3] = bmfma(a, b, acc[ks & 3]);
        }
        #pragma unroll
        for (int ks = 24; ks < 32; ++ks) {
            short8 a = *reinterpret_cast<const short8*>(&hA[(ks * 64 + lane) * 8]);
            short8 b = *reinterpret_cast<const short8*>(wstream + (size_t)(ks - 24) * 2048);
            acc[ks & 3] = bmfma(a, b, acc[ks & 3]);
        }

        // ---- gather z across waves (wave w = gate w) ----
        f32x4 z4 = (acc[0] + acc[1]) + (acc[2] + acc[3]);
        #pragma unroll
        for (int i = 0; i < 4; ++i)               // C layout: col=lane&15, row=hi*4+i
            smZ[(hi * 4 + i) * 65 + w * 16 + r] = z4[i];
        __syncthreads();

        float zf = smZ[erow * 65 + ecol]      + bfv;
        float zi = smZ[erow * 65 + 16 + ecol] + biv;
        float zc = smZ[erow * 65 + 32 + ecol] + bcv;
        float zo = smZ[erow * 65 + 48 + ecol] + bov;
        float fg  = 1.f / (1.f + __expf(-zf));
        float ig  = 1.f / (1.f + __expf(-zi));
        float cg_ = 2.f / (1.f + __expf(-2.f * zc)) - 1.f;
        float og  = 1.f / (1.f + __expf(-zo));
        creg = fg * creg + ig * cg_;
        float nh = og * (2.f / (1.f + __expf(-2.f * creg)) - 1.f);

        // ---- publish h into frag-order tile (write-through agent stores) + out (NT) ----
        unsigned mybits = (unsigned)(unsigned short)f2bf(nh);
        unsigned pbits  = __shfl_xor(mybits, 1);  // partner col (ecol^1), same row
        short* hnext_tile = hb + (size_t)((t + 1) & 1) * (BATCH * H_DIM) + bt * 16384;
        if ((tid & 1) == 0) {
            unsigned val = mybits | (pbits << 16);
            __hip_atomic_store(reinterpret_cast<unsigned*>(hnext_tile + pub_off),
                               val, __ATOMIC_RELAXED, __HIP_MEMORY_SCOPE_AGENT);
        }
        __builtin_nontemporal_store(nh, out + (size_t)t * (BATCH * H_DIM) + (size_t)row_g * H_DIM + col_g);

        // ---- arrive: drain stores, ONE flat RMW on my bt-line ----
        __syncthreads();
        if (tid == 0)
            __hip_atomic_fetch_add(mybarr, 1, __ATOMIC_RELAXED, __HIP_MEMORY_SCOPE_AGENT);

        // ---- shadow: stage x(t+1) (frag-order, fully contiguous) ----
        if (t + 1 < T_STEPS) {
            const short* xtile = xb + ((size_t)(t + 1) * 4 + bt) * (1024 * 8);
            #pragma unroll
            for (int q = 0; q < 4; ++q) {
                int sl = q * 256 + tid;
                *reinterpret_cast<short8*>(&xA[sl * 8]) =
                    *reinterpret_cast<const short8*>(xtile + (size_t)sl * 8);
            }
        }
    }
}

extern "C" void kernel_launch(void* const* d_in, const int* in_sizes, int n_in,
                              void* d_out, int out_size, void* d_ws, size_t ws_size,
                              hipStream_t stream) {
    const float* x   = (const float*)d_in[0];
    const float* Wf  = (const float*)d_in[1];
    const float* Wi  = (const float*)d_in[2];
    const float* Wc  = (const float*)d_in[3];
    const float* Wo  = (const float*)d_in[4];
    const float* bf_ = (const float*)d_in[5];
    const float* bi_ = (const float*)d_in[6];
    const float* bc_ = (const float*)d_in[7];
    const float* bo_ = (const float*)d_in[8];
    float* out = (float*)d_out;

    char*  ws    = (char*)d_ws;
    int*   syncp = (int*)(ws + WS_SYNC);
    short* hbuf  = (short*)(ws + WS_HB);
    short* xb    = (short*)(ws + WS_XB);
    short* Wpk   = (short*)(ws + WS_WPK);

    hipFuncSetAttribute((const void*)lstm_persistent,
                        hipFuncAttributeMaxDynamicSharedMemorySize, LDS_TOTAL);

    const float* Ws[4] = {Wf, Wi, Wc, Wo};
    for (int g = 0; g < 4; ++g)
        pack_w_kernel<<<(H_DIM * KDIM) / 256, 256, 0, stream>>>(Ws[g], Wpk, g);
    xconv_kernel<<<(T_STEPS * BATCH * IN_DIM) / (256 * 8), 256, 0, stream>>>(x, xb);
    init_state_kernel<<<256, 256, 0, stream>>>(syncp, (int*)hbuf);

    const short* Wpk_c = Wpk; const short* xb_c = xb;
    void* args[] = {(void*)&Wpk_c, (void*)&xb_c, (void*)&hbuf, (void*)&out,
                    (void*)&bf_, (void*)&bi_, (void*)&bc_, (void*)&bo_, (void*)&syncp};
    hipLaunchCooperativeKernel((const void*)lstm_persistent, dim3(NWG), dim3(NTHREADS),
                               args, LDS_TOTAL, stream);
}